// Round 10
// baseline (489.874 us; speedup 1.0000x reference)
//
#include <hip/hip_runtime.h>
#include <hip/hip_bf16.h>

#define NROWS 100000

typedef __attribute__((ext_vector_type(8))) short bf16x8;
typedef __attribute__((ext_vector_type(4))) float f32x4;
typedef float f32x4a8 __attribute__((ext_vector_type(4), aligned(8)));

__device__ __forceinline__ short f2b(float f) {
  __hip_bfloat16 h = __float2bfloat16(f);
  short s;
  __builtin_memcpy(&s, &h, sizeof(s));
  return s;
}

__device__ __forceinline__ float b2f(unsigned short u) {
  unsigned v = ((unsigned)u) << 16;
  float f;
  __builtin_memcpy(&f, &v, sizeof(f));
  return f;
}

__device__ __forceinline__ float sigf(float x) { return 1.f / (1.f + __expf(-x)); }
__device__ __forceinline__ float tanh_f(float x) { return 1.f - 2.f / (__expf(2.f * x) + 1.f); }

__device__ __forceinline__ void gload_lds16(const void* g, void* l) {
  __builtin_amdgcn_global_load_lds((const __attribute__((address_space(1))) unsigned int*)g,
                                   (__attribute__((address_space(3))) unsigned int*)l, 16, 0, 0);
}

// ---------------- weight packing ----------------
// New m-split layout (3 m-blocks of 64 cols each; gates stay within a block):
// B1: [kt=18][mb=3][ct=16][lane=64][b=8]; ct = gate*4 + mtl (4 gates x 4 mtl);
//     m = mb*64 + mtl*16 + (lane&15); k = kt*32+(lane>>4)*8+b.
//     K-rows: e(0:300)|tag(300:350)|tagp(350:400)|h(400:568)|bias(568)|0.
// B2: [kt=14][mb=3][ct=24][lane=64][b=8]; ct<20 real (5 gates x 4 mtl), 20..23 zero pad;
//     K-rows: tag(0:50)|tagp(50:100)|k(100:268)|h1(268:436)|bias(436)|0. Uk only gates 0-3.
__global__ void pack_weights(const float* __restrict__ We_l, const float* __restrict__ Wt_l,
                             const float* __restrict__ Wtp_l, const float* __restrict__ Uh_l,
                             const float* __restrict__ b_l,
                             const float* __restrict__ Wt_n, const float* __restrict__ Wtp_n,
                             const float* __restrict__ Uh_n, const float* __restrict__ Uk_n,
                             const float* __restrict__ b_n,
                             unsigned short* __restrict__ B1, unsigned short* __restrict__ B2) {
  const int NB1 = 18 * 3 * 16 * 512;
  const int NB2 = 14 * 3 * 24 * 512;
  int idx = blockIdx.x * blockDim.x + threadIdx.x;
  if (idx < NB1) {
    int b = idx & 7, lane = (idx >> 3) & 63, t = idx >> 9;
    int ct = t % 16, mb = (t / 16) % 3, kt = t / 48;
    int k = kt * 32 + ((lane >> 4) << 3) + b;
    int gate = ct >> 2, mtl = ct & 3;
    int m = mb * 64 + mtl * 16 + (lane & 15);
    float v = 0.f;
    if (m < 168) {
      int col = gate * 168 + m;
      if (k < 300)       v = We_l[k * 672 + col];
      else if (k < 350)  v = Wt_l[(k - 300) * 672 + col];
      else if (k < 400)  v = Wtp_l[(k - 350) * 672 + col];
      else if (k < 568)  v = Uh_l[(k - 400) * 672 + col];
      else if (k == 568) v = b_l[col];
    }
    B1[idx] = (unsigned short)f2b(v);
  } else if (idx < NB1 + NB2) {
    int j = idx - NB1;
    int b = j & 7, lane = (j >> 3) & 63, t = j >> 9;
    int ct = t % 24, mb = (t / 24) % 3, kt = t / 72;
    int k = kt * 32 + ((lane >> 4) << 3) + b;
    int gate = ct >> 2, mtl = ct & 3;
    int m = mb * 64 + mtl * 16 + (lane & 15);
    float v = 0.f;
    if (ct < 20 && m < 168) {
      int col = gate * 168 + m;
      if (k < 50)        v = Wt_n[k * 840 + col];
      else if (k < 100)  v = Wtp_n[(k - 50) * 840 + col];
      else if (k < 268)  v = (gate < 4) ? Uk_n[(k - 100) * 672 + gate * 168 + m] : 0.f;
      else if (k < 436)  v = Uh_n[(k - 268) * 840 + col];
      else if (k == 436) v = b_n[col];
    }
    B2[j] = (unsigned short)f2b(v);
  }
}

// aligned-8 float4 load (tag/tagp rows are only 8B aligned)
__device__ __forceinline__ float4 ld4a8(const float* __restrict__ p) {
  f32x4a8 v = *(const f32x4a8*)p;
  return make_float4(v[0], v[1], v[2], v[3]);
}

// ---------------- GEMM1: leaf cell ----------------
// Block = 64 rows x 64 m-cols x 4 gates. 8 waves = 2 rw x 4 cw (cw = m-tile).
// acc/thread = 32 f32 -> 4 waves/SIMD, 2 blocks/CU.
#define G1_NKT 18
#define G1_LOADS 2      // 16 KB / 512 threads / 16 B

__global__ __launch_bounds__(512, 4) void gemm1_kernel(
    const float* __restrict__ e, const float* __restrict__ tg, const float* __restrict__ tp,
    const float* __restrict__ hp, const float* __restrict__ cprev,
    const char* __restrict__ B1, unsigned short* __restrict__ c1buf,
    unsigned short* __restrict__ h1buf) {
  __shared__ char bb[2][16 * 1024];
  __shared__ char ab[2][4096];
  const int tid = threadIdx.x;
  const int wave = tid >> 6, ln = tid & 63;
  const int rw = wave >> 2, cw = wave & 3;
  const int rowblk = blockIdx.x / 3, mb = blockIdx.x % 3;
  const int rbase = rowblk * 64 + rw * 32;
  const int c = ln & 15, rg = ln >> 4;

  // A staging geometry: thread covers (rowt = tid>>3, 4 f32 cols at (tid&7)*4)
  const int srowt = tid >> 3;
  const int sks = tid & 7;
  int srow = rowblk * 64 + srowt;
  if (srow >= NROWS) srow = NROWS - 1;
  const int sphys = srowt * 64 + ((((sks >> 1) ^ ((srowt >> 1) & 3)) << 4)) + ((sks & 1) << 3);

  // A-chunk loader: X1 = [e|tag|tagp|h|bias(568)|0], c4 = kt*32 + sks*4
  auto loadA = [&](int kt) -> float4 {
    const int c4 = kt * 32 + sks * 4;
    if (c4 + 4 <= 300) return *(const float4*)(e + srow * 300 + c4);
    if (c4 >= 300 && c4 + 4 <= 348) return ld4a8(tg + srow * 50 + (c4 - 300));
    if (c4 == 348)
      return make_float4(tg[srow * 50 + 48], tg[srow * 50 + 49], tp[srow * 50 + 0], tp[srow * 50 + 1]);
    if (c4 >= 352 && c4 + 4 <= 400) return ld4a8(tp + srow * 50 + (c4 - 350));
    if (c4 >= 400 && c4 + 4 <= 568) return *(const float4*)(hp + srow * 168 + (c4 - 400));
    if (c4 == 568) return make_float4(1.f, 0.f, 0.f, 0.f);
    return make_float4(0.f, 0.f, 0.f, 0.f);
  };
  auto storeA = [&](int buf, float4 v) {
    ushort4 w;
    w.x = (unsigned short)f2b(v.x); w.y = (unsigned short)f2b(v.y);
    w.z = (unsigned short)f2b(v.z); w.w = (unsigned short)f2b(v.w);
    *(ushort4*)&ab[buf][sphys] = w;
  };

  f32x4 acc[2][4];
  const f32x4 z4 = {0.f, 0.f, 0.f, 0.f};
#pragma unroll
  for (int a = 0; a < 2; ++a)
#pragma unroll
    for (int t = 0; t < 4; ++t) acc[a][t] = z4;

  // prologue: stage kt=0; prefetch A(1) into regs
  storeA(0, loadA(0));
  const char* Bbase = B1 + (size_t)mb * 16384;
#pragma unroll
  for (int j = 0; j < G1_LOADS; ++j)
    gload_lds16(Bbase + (j * 512 + tid) * 16, &bb[0][(j * 512 + (wave << 6)) * 16]);
  float4 av = loadA(1);
  __syncthreads();

  const int r0t = rw * 32 + c, r1t = rw * 32 + 16 + c;
  const int aoff0 = r0t * 64 + ((rg ^ ((r0t >> 1) & 3)) << 4);
  const int aoff1 = r1t * 64 + ((rg ^ ((r1t >> 1) & 3)) << 4);

#pragma unroll
  for (int kt = 0; kt < G1_NKT; ++kt) {
    const int cur = kt & 1, nxt = cur ^ 1;
    bf16x8 a0 = *(const bf16x8*)&ab[cur][aoff0];
    bf16x8 a1 = *(const bf16x8*)&ab[cur][aoff1];
    bf16x8 bfr[4];
#pragma unroll
    for (int g = 0; g < 4; ++g)
      bfr[g] = *(const bf16x8*)&bb[cur][((((g << 2) + cw) << 6) + ln) * 16];
    if (kt + 1 < G1_NKT) {
      storeA(nxt, av);
      if (kt + 2 < G1_NKT) av = loadA(kt + 2);
      const char* g = B1 + ((size_t)(kt + 1) * 3 + mb) * 16384;
#pragma unroll
      for (int j = 0; j < G1_LOADS; ++j)
        gload_lds16(g + (j * 512 + tid) * 16, &bb[nxt][(j * 512 + (wave << 6)) * 16]);
    }
#pragma unroll
    for (int g = 0; g < 4; ++g) {
      acc[0][g] = __builtin_amdgcn_mfma_f32_16x16x32_bf16(a0, bfr[g], acc[0][g], 0, 0, 0);
      acc[1][g] = __builtin_amdgcn_mfma_f32_16x16x32_bf16(a1, bfr[g], acc[1][g], 0, 0, 0);
    }
    __syncthreads();
  }

  // epilogue (bias already in acc via K-row 568)
  const int m = mb * 64 + cw * 16 + c;
  if (m < 168) {
#pragma unroll
    for (int rt = 0; rt < 2; ++rt) {
#pragma unroll
      for (int reg = 0; reg < 4; ++reg) {
        const int row = rbase + rt * 16 + (rg << 2) + reg;
        if (row >= NROWS) continue;
        const float iv = acc[rt][0][reg];
        const float ov = acc[rt][1][reg];
        const float fv = acc[rt][2][reg];
        const float uv = acc[rt][3][reg];
        const int off = row * 168 + m;
        const float cp = cprev[off];
        const float c1 = sigf(iv) * tanh_f(uv) + sigf(fv) * cp;
        const float h1 = sigf(ov) * tanh_f(c1);
        c1buf[off] = (unsigned short)f2b(c1);
        h1buf[off] = (unsigned short)f2b(h1);
      }
    }
  }
}

// ---------------- GEMM2: node cell ----------------
#define G2_NKT 14
#define G2_LOADS 3      // 24 KB / 512 threads / 16 B

__global__ __launch_bounds__(512, 4) void gemm2_kernel(
    const float* __restrict__ tg, const float* __restrict__ tp, const float* __restrict__ kk,
    const float* __restrict__ q, const char* __restrict__ B2,
    const unsigned short* __restrict__ c1buf, const unsigned short* __restrict__ h1buf,
    float* __restrict__ out) {
  __shared__ char bb[2][24 * 1024];
  __shared__ char ab[2][4096];
  const int tid = threadIdx.x;
  const int wave = tid >> 6, ln = tid & 63;
  const int rw = wave >> 2, cw = wave & 3;
  const int rowblk = blockIdx.x / 3, mb = blockIdx.x % 3;
  const int rbase = rowblk * 64 + rw * 32;
  const int c = ln & 15, rg = ln >> 4;

  const int srowt = tid >> 3;
  const int sks = tid & 7;
  int srow = rowblk * 64 + srowt;
  if (srow >= NROWS) srow = NROWS - 1;
  const int sphys = srowt * 64 + ((((sks >> 1) ^ ((srowt >> 1) & 3)) << 4)) + ((sks & 1) << 3);

  // X2 = [tag(0:50)|tagp(50:100)|k(100:268)|h1(268:436)|bias(436)|0]
  auto loadA = [&](int kt) -> float4 {
    const int c4 = kt * 32 + sks * 4;
    if (c4 + 4 <= 48) return ld4a8(tg + srow * 50 + c4);
    if (c4 == 48)
      return make_float4(tg[srow * 50 + 48], tg[srow * 50 + 49], tp[srow * 50 + 0], tp[srow * 50 + 1]);
    if (c4 >= 52 && c4 + 4 <= 100) return ld4a8(tp + srow * 50 + (c4 - 50));
    if (c4 >= 100 && c4 + 4 <= 268) return *(const float4*)(kk + srow * 168 + (c4 - 100));
    if (c4 >= 268 && c4 + 4 <= 436) {
      ushort4 w = *(const ushort4*)(h1buf + srow * 168 + (c4 - 268));
      return make_float4(b2f(w.x), b2f(w.y), b2f(w.z), b2f(w.w));
    }
    if (c4 == 436) return make_float4(1.f, 0.f, 0.f, 0.f);
    return make_float4(0.f, 0.f, 0.f, 0.f);
  };
  auto storeA = [&](int buf, float4 v) {
    ushort4 w;
    w.x = (unsigned short)f2b(v.x); w.y = (unsigned short)f2b(v.y);
    w.z = (unsigned short)f2b(v.z); w.w = (unsigned short)f2b(v.w);
    *(ushort4*)&ab[buf][sphys] = w;
  };

  f32x4 acc[2][5];
  const f32x4 z4 = {0.f, 0.f, 0.f, 0.f};
#pragma unroll
  for (int a = 0; a < 2; ++a)
#pragma unroll
    for (int t = 0; t < 5; ++t) acc[a][t] = z4;

  storeA(0, loadA(0));
  const char* Bbase = B2 + (size_t)mb * 24576;
#pragma unroll
  for (int j = 0; j < G2_LOADS; ++j)
    gload_lds16(Bbase + (j * 512 + tid) * 16, &bb[0][(j * 512 + (wave << 6)) * 16]);
  float4 av = loadA(1);
  __syncthreads();

  const int r0t = rw * 32 + c, r1t = rw * 32 + 16 + c;
  const int aoff0 = r0t * 64 + ((rg ^ ((r0t >> 1) & 3)) << 4);
  const int aoff1 = r1t * 64 + ((rg ^ ((r1t >> 1) & 3)) << 4);

#pragma unroll
  for (int kt = 0; kt < G2_NKT; ++kt) {
    const int cur = kt & 1, nxt = cur ^ 1;
    bf16x8 a0 = *(const bf16x8*)&ab[cur][aoff0];
    bf16x8 a1 = *(const bf16x8*)&ab[cur][aoff1];
    bf16x8 bfr[5];
#pragma unroll
    for (int g = 0; g < 5; ++g)
      bfr[g] = *(const bf16x8*)&bb[cur][((((g << 2) + cw) << 6) + ln) * 16];
    if (kt + 1 < G2_NKT) {
      storeA(nxt, av);
      if (kt + 2 < G2_NKT) av = loadA(kt + 2);
      const char* g = B2 + ((size_t)(kt + 1) * 3 + mb) * 24576;
#pragma unroll
      for (int j = 0; j < G2_LOADS; ++j)
        gload_lds16(g + (j * 512 + tid) * 16, &bb[nxt][(j * 512 + (wave << 6)) * 16]);
    }
#pragma unroll
    for (int g = 0; g < 5; ++g) {
      acc[0][g] = __builtin_amdgcn_mfma_f32_16x16x32_bf16(a0, bfr[g], acc[0][g], 0, 0, 0);
      acc[1][g] = __builtin_amdgcn_mfma_f32_16x16x32_bf16(a1, bfr[g], acc[1][g], 0, 0, 0);
    }
    __syncthreads();
  }

  const int m = mb * 64 + cw * 16 + c;
  if (m < 168) {
#pragma unroll
    for (int rt = 0; rt < 2; ++rt) {
#pragma unroll
      for (int reg = 0; reg < 4; ++reg) {
        const int row = rbase + rt * 16 + (rg << 2) + reg;
        if (row >= NROWS) continue;
        const float i2 = acc[rt][0][reg];
        const float o2 = acc[rt][1][reg];
        const float fl2 = acc[rt][2][reg];
        const float fd2 = acc[rt][3][reg];
        const float u2 = acc[rt][4][reg];
        const int off = row * 168 + m;
        const float c1 = b2f(c1buf[off]);
        const float qv = q[off];
        const float c2 = sigf(i2) * tanh_f(u2) + sigf(fd2) * qv + sigf(fl2) * c1;
        const float h2 = sigf(o2) * tanh_f(c2);
        out[row * 336 + m] = h2;
        out[row * 336 + 168 + m] = c2;
      }
    }
  }
}

extern "C" void kernel_launch(void* const* d_in, const int* in_sizes, int n_in,
                              void* d_out, int out_size, void* d_ws, size_t ws_size,
                              hipStream_t stream) {
  const float* e     = (const float*)d_in[0];
  const float* tag   = (const float*)d_in[1];
  const float* tagp  = (const float*)d_in[2];
  const float* hprev = (const float*)d_in[3];
  const float* cprev = (const float*)d_in[4];
  const float* kk    = (const float*)d_in[5];
  const float* q     = (const float*)d_in[6];
  const float* We_l  = (const float*)d_in[7];
  const float* Wt_l  = (const float*)d_in[8];
  const float* Wtp_l = (const float*)d_in[9];
  const float* Uh_l  = (const float*)d_in[10];
  const float* b_l   = (const float*)d_in[11];
  const float* Wt_n  = (const float*)d_in[12];
  const float* Wtp_n = (const float*)d_in[13];
  const float* Uh_n  = (const float*)d_in[14];
  const float* Uk_n  = (const float*)d_in[15];
  const float* b_n   = (const float*)d_in[16];
  float* out = (float*)d_out;

  char* ws = (char*)d_ws;
  unsigned short* B1 = (unsigned short*)ws;                               // 884,736 B
  unsigned short* B2 = (unsigned short*)(ws + (1 << 20));                 // 1,032,192 B
  unsigned short* c1buf = (unsigned short*)(ws + (3 << 20));              // 33,600,000 B
  unsigned short* h1buf = (unsigned short*)(ws + (3 << 20) + 33600000);   // 33,600,000 B

  const int NB = 18 * 3 * 16 * 512 + 14 * 3 * 24 * 512;
  pack_weights<<<(NB + 255) / 256, 256, 0, stream>>>(We_l, Wt_l, Wtp_l, Uh_l, b_l,
                                                     Wt_n, Wtp_n, Uh_n, Uk_n, b_n, B1, B2);

  const int nblk = ((NROWS + 63) / 64) * 3;  // 1563 * 3 = 4689
  gemm1_kernel<<<nblk, 512, 0, stream>>>(e, tag, tagp, hprev, cprev,
                                         (const char*)B1, c1buf, h1buf);
  gemm2_kernel<<<nblk, 512, 0, stream>>>(tag, tagp, kk, q,
                                         (const char*)B2, c1buf, h1buf, out);
}

// Round 11
// 428.299 us; speedup vs baseline: 1.1438x; 1.1438x over previous
//
#include <hip/hip_runtime.h>
#include <hip/hip_bf16.h>

#define NROWS 100000
#define NRB 1563  // ceil(NROWS/64)

typedef __attribute__((ext_vector_type(8))) short bf16x8;
typedef __attribute__((ext_vector_type(4))) float f32x4;
typedef float f32x4a8 __attribute__((ext_vector_type(4), aligned(8)));

__device__ __forceinline__ short f2b(float f) {
  __hip_bfloat16 h = __float2bfloat16(f);
  short s;
  __builtin_memcpy(&s, &h, sizeof(s));
  return s;
}

__device__ __forceinline__ float b2f(unsigned short u) {
  unsigned v = ((unsigned)u) << 16;
  float f;
  __builtin_memcpy(&f, &v, sizeof(f));
  return f;
}

__device__ __forceinline__ float sigf(float x) { return 1.f / (1.f + __expf(-x)); }
__device__ __forceinline__ float tanh_f(float x) { return 1.f - 2.f / (__expf(2.f * x) + 1.f); }

__device__ __forceinline__ void gload_lds16(const void* g, void* l) {
  __builtin_amdgcn_global_load_lds((const __attribute__((address_space(1))) unsigned int*)g,
                                   (__attribute__((address_space(3))) unsigned int*)l, 16, 0, 0);
}

// ---------------- weight packing (unchanged from round 10) ----------------
// B1: [kt=18][mb=3][ct=16][lane=64][b=8]; ct = gate*4 + mtl;
//     m = mb*64 + mtl*16 + (lane&15); k = kt*32+(lane>>4)*8+b.
//     K-rows: e(0:300)|tag(300:350)|tagp(350:400)|h(400:568)|bias(568)|0.
// B2: [kt=14][mb=3][ct=24][lane=64][b=8]; ct<20 real; K-rows:
//     tag(0:50)|tagp(50:100)|k(100:268)|h1(268:436)|bias(436)|0. Uk only gates 0-3.
__global__ void pack_weights(const float* __restrict__ We_l, const float* __restrict__ Wt_l,
                             const float* __restrict__ Wtp_l, const float* __restrict__ Uh_l,
                             const float* __restrict__ b_l,
                             const float* __restrict__ Wt_n, const float* __restrict__ Wtp_n,
                             const float* __restrict__ Uh_n, const float* __restrict__ Uk_n,
                             const float* __restrict__ b_n,
                             unsigned short* __restrict__ B1, unsigned short* __restrict__ B2) {
  const int NB1 = 18 * 3 * 16 * 512;
  const int NB2 = 14 * 3 * 24 * 512;
  int idx = blockIdx.x * blockDim.x + threadIdx.x;
  if (idx < NB1) {
    int b = idx & 7, lane = (idx >> 3) & 63, t = idx >> 9;
    int ct = t % 16, mb = (t / 16) % 3, kt = t / 48;
    int k = kt * 32 + ((lane >> 4) << 3) + b;
    int gate = ct >> 2, mtl = ct & 3;
    int m = mb * 64 + mtl * 16 + (lane & 15);
    float v = 0.f;
    if (m < 168) {
      int col = gate * 168 + m;
      if (k < 300)       v = We_l[k * 672 + col];
      else if (k < 350)  v = Wt_l[(k - 300) * 672 + col];
      else if (k < 400)  v = Wtp_l[(k - 350) * 672 + col];
      else if (k < 568)  v = Uh_l[(k - 400) * 672 + col];
      else if (k == 568) v = b_l[col];
    }
    B1[idx] = (unsigned short)f2b(v);
  } else if (idx < NB1 + NB2) {
    int j = idx - NB1;
    int b = j & 7, lane = (j >> 3) & 63, t = j >> 9;
    int ct = t % 24, mb = (t / 24) % 3, kt = t / 72;
    int k = kt * 32 + ((lane >> 4) << 3) + b;
    int gate = ct >> 2, mtl = ct & 3;
    int m = mb * 64 + mtl * 16 + (lane & 15);
    float v = 0.f;
    if (ct < 20 && m < 168) {
      int col = gate * 168 + m;
      if (k < 50)        v = Wt_n[k * 840 + col];
      else if (k < 100)  v = Wtp_n[(k - 50) * 840 + col];
      else if (k < 268)  v = (gate < 4) ? Uk_n[(k - 100) * 672 + gate * 168 + m] : 0.f;
      else if (k < 436)  v = Uh_n[(k - 268) * 840 + col];
      else if (k == 436) v = b_n[col];
    }
    B2[j] = (unsigned short)f2b(v);
  }
}

__device__ __forceinline__ float4 ld4a8(const float* __restrict__ p) {
  f32x4a8 v = *(const f32x4a8*)p;
  return make_float4(v[0], v[1], v[2], v[3]);
}

// XCD-sibling decode: 3 m-split siblings of one row-block land on one XCD.
__device__ __forceinline__ void xcd_decode(int bid, int& rowblk, int& mb) {
  const int xcd = bid & 7;
  const int j = bid >> 3;
  rowblk = (j / 3) * 8 + xcd;
  mb = j % 3;
}

// ---------------- GEMM1: leaf cell ----------------
// Block = 64 rows x 64 m-cols x 4 gates. 8 waves = 2 rw x 4 cw.
// Triple-buffered B via global_load_lds + counted-vmcnt raw barrier (T4).
#define G1_NKT 18
#define G1_LOADS 2

__global__ __launch_bounds__(512, 4) void gemm1_kernel(
    const float* __restrict__ e, const float* __restrict__ tg, const float* __restrict__ tp,
    const float* __restrict__ hp, const float* __restrict__ cprev,
    const char* __restrict__ B1, unsigned short* __restrict__ c1buf,
    unsigned short* __restrict__ h1buf) {
  __shared__ char bb[3][16 * 1024];
  __shared__ char ab[2][4096];
  int rowblk, mb;
  xcd_decode(blockIdx.x, rowblk, mb);
  if (rowblk >= NRB) return;
  const int tid = threadIdx.x;
  const int wave = tid >> 6, ln = tid & 63;
  const int rw = wave >> 2, cw = wave & 3;
  const int rbase = rowblk * 64 + rw * 32;
  const int c = ln & 15, rg = ln >> 4;

  const int srowt = tid >> 3;
  const int sks = tid & 7;
  int srow = rowblk * 64 + srowt;
  if (srow >= NROWS) srow = NROWS - 1;
  const int sphys = srowt * 64 + ((((sks >> 1) ^ ((srowt >> 1) & 3)) << 4)) + ((sks & 1) << 3);

  auto loadA = [&](int kt) -> float4 {
    const int c4 = kt * 32 + sks * 4;
    if (c4 + 4 <= 300) return *(const float4*)(e + srow * 300 + c4);
    if (c4 >= 300 && c4 + 4 <= 348) return ld4a8(tg + srow * 50 + (c4 - 300));
    if (c4 == 348)
      return make_float4(tg[srow * 50 + 48], tg[srow * 50 + 49], tp[srow * 50 + 0], tp[srow * 50 + 1]);
    if (c4 >= 352 && c4 + 4 <= 400) return ld4a8(tp + srow * 50 + (c4 - 350));
    if (c4 >= 400 && c4 + 4 <= 568) return *(const float4*)(hp + srow * 168 + (c4 - 400));
    if (c4 == 568) return make_float4(1.f, 0.f, 0.f, 0.f);
    return make_float4(0.f, 0.f, 0.f, 0.f);
  };
  auto storeA = [&](int buf, float4 v) {
    ushort4 w;
    w.x = (unsigned short)f2b(v.x); w.y = (unsigned short)f2b(v.y);
    w.z = (unsigned short)f2b(v.z); w.w = (unsigned short)f2b(v.w);
    *(ushort4*)&ab[buf][sphys] = w;
  };
  auto stageB = [&](int kt, int buf) {
    const char* g = B1 + ((size_t)kt * 3 + mb) * 16384;
#pragma unroll
    for (int j = 0; j < G1_LOADS; ++j)
      gload_lds16(g + (j * 512 + tid) * 16, &bb[buf][(j * 512 + (wave << 6)) * 16]);
  };

  f32x4 acc[2][4];
  const f32x4 z4 = {0.f, 0.f, 0.f, 0.f};
#pragma unroll
  for (int a = 0; a < 2; ++a)
#pragma unroll
    for (int t = 0; t < 4; ++t) acc[a][t] = z4;

  // prologue: A(0)->ab0, B(0)->bb0, av=A(1), B(1)->bb1; drain B(0)+storeA.
  storeA(0, loadA(0));
  stageB(0, 0);
  float4 av = loadA(1);
  stageB(1, 1);
  asm volatile("s_waitcnt vmcnt(3) lgkmcnt(0)" ::: "memory");  // av + B(1)=2 remain
  __builtin_amdgcn_s_barrier();

  const int r0t = rw * 32 + c, r1t = rw * 32 + 16 + c;
  const int aoff0 = r0t * 64 + ((rg ^ ((r0t >> 1) & 3)) << 4);
  const int aoff1 = r1t * 64 + ((rg ^ ((r1t >> 1) & 3)) << 4);

#pragma unroll
  for (int kt = 0; kt < G1_NKT; ++kt) {
    const int curB = kt % 3;
    const int curA = kt & 1;
    bf16x8 a0 = *(const bf16x8*)&ab[curA][aoff0];
    bf16x8 a1 = *(const bf16x8*)&ab[curA][aoff1];
    bf16x8 bfr[4];
#pragma unroll
    for (int g = 0; g < 4; ++g)
      bfr[g] = *(const bf16x8*)&bb[curB][((((g << 2) + cw) << 6) + ln) * 16];
    if (kt + 1 < G1_NKT) storeA(curA ^ 1, av);
    if (kt + 2 < G1_NKT) {
      av = loadA(kt + 2);
      stageB(kt + 2, (kt + 2) % 3);
    }
#pragma unroll
    for (int g = 0; g < 4; ++g) {
      acc[0][g] = __builtin_amdgcn_mfma_f32_16x16x32_bf16(a0, bfr[g], acc[0][g], 0, 0, 0);
      acc[1][g] = __builtin_amdgcn_mfma_f32_16x16x32_bf16(a1, bfr[g], acc[1][g], 0, 0, 0);
    }
    if (kt + 1 < G1_NKT) {
      if (kt + 2 < G1_NKT) {
        // keep av + B(kt+2) in flight; ensures B(kt+1) landed
        asm volatile("s_waitcnt vmcnt(3) lgkmcnt(0)" ::: "memory");
      } else {
        asm volatile("s_waitcnt vmcnt(0) lgkmcnt(0)" ::: "memory");
      }
      __builtin_amdgcn_s_barrier();
    }
  }

  // epilogue (bias folded via K-row 568)
  const int m = mb * 64 + cw * 16 + c;
  if (m < 168) {
#pragma unroll
    for (int rt = 0; rt < 2; ++rt) {
#pragma unroll
      for (int reg = 0; reg < 4; ++reg) {
        const int row = rbase + rt * 16 + (rg << 2) + reg;
        if (row >= NROWS) continue;
        const float iv = acc[rt][0][reg];
        const float ov = acc[rt][1][reg];
        const float fv = acc[rt][2][reg];
        const float uv = acc[rt][3][reg];
        const int off = row * 168 + m;
        const float cp = cprev[off];
        const float c1 = sigf(iv) * tanh_f(uv) + sigf(fv) * cp;
        const float h1 = sigf(ov) * tanh_f(c1);
        c1buf[off] = (unsigned short)f2b(c1);
        h1buf[off] = (unsigned short)f2b(h1);
      }
    }
  }
}

// ---------------- GEMM2: node cell ----------------
#define G2_NKT 14
#define G2_LOADS 3

__global__ __launch_bounds__(512, 4) void gemm2_kernel(
    const float* __restrict__ tg, const float* __restrict__ tp, const float* __restrict__ kk,
    const float* __restrict__ q, const char* __restrict__ B2,
    const unsigned short* __restrict__ c1buf, const unsigned short* __restrict__ h1buf,
    float* __restrict__ out) {
  __shared__ char bb[3][24 * 1024];
  __shared__ char ab[2][4096];
  int rowblk, mb;
  xcd_decode(blockIdx.x, rowblk, mb);
  if (rowblk >= NRB) return;
  const int tid = threadIdx.x;
  const int wave = tid >> 6, ln = tid & 63;
  const int rw = wave >> 2, cw = wave & 3;
  const int rbase = rowblk * 64 + rw * 32;
  const int c = ln & 15, rg = ln >> 4;

  const int srowt = tid >> 3;
  const int sks = tid & 7;
  int srow = rowblk * 64 + srowt;
  if (srow >= NROWS) srow = NROWS - 1;
  const int sphys = srowt * 64 + ((((sks >> 1) ^ ((srowt >> 1) & 3)) << 4)) + ((sks & 1) << 3);

  // X2 = [tag(0:50)|tagp(50:100)|k(100:268)|h1(268:436)|bias(436)|0]
  auto loadA = [&](int kt) -> float4 {
    const int c4 = kt * 32 + sks * 4;
    if (c4 + 4 <= 48) return ld4a8(tg + srow * 50 + c4);
    if (c4 == 48)
      return make_float4(tg[srow * 50 + 48], tg[srow * 50 + 49], tp[srow * 50 + 0], tp[srow * 50 + 1]);
    if (c4 >= 52 && c4 + 4 <= 100) return ld4a8(tp + srow * 50 + (c4 - 50));
    if (c4 >= 100 && c4 + 4 <= 268) return *(const float4*)(kk + srow * 168 + (c4 - 100));
    if (c4 >= 268 && c4 + 4 <= 436) {
      ushort4 w = *(const ushort4*)(h1buf + srow * 168 + (c4 - 268));
      return make_float4(b2f(w.x), b2f(w.y), b2f(w.z), b2f(w.w));
    }
    if (c4 == 436) return make_float4(1.f, 0.f, 0.f, 0.f);
    return make_float4(0.f, 0.f, 0.f, 0.f);
  };
  auto storeA = [&](int buf, float4 v) {
    ushort4 w;
    w.x = (unsigned short)f2b(v.x); w.y = (unsigned short)f2b(v.y);
    w.z = (unsigned short)f2b(v.z); w.w = (unsigned short)f2b(v.w);
    *(ushort4*)&ab[buf][sphys] = w;
  };
  auto stageB = [&](int kt, int buf) {
    const char* g = B2 + ((size_t)kt * 3 + mb) * 24576;
#pragma unroll
    for (int j = 0; j < G2_LOADS; ++j)
      gload_lds16(g + (j * 512 + tid) * 16, &bb[buf][(j * 512 + (wave << 6)) * 16]);
  };

  f32x4 acc[2][5];
  const f32x4 z4 = {0.f, 0.f, 0.f, 0.f};
#pragma unroll
  for (int a = 0; a < 2; ++a)
#pragma unroll
    for (int t = 0; t < 5; ++t) acc[a][t] = z4;

  storeA(0, loadA(0));
  stageB(0, 0);
  float4 av = loadA(1);
  stageB(1, 1);
  asm volatile("s_waitcnt vmcnt(4) lgkmcnt(0)" ::: "memory");  // av + B(1)=3 remain
  __builtin_amdgcn_s_barrier();

  const int r0t = rw * 32 + c, r1t = rw * 32 + 16 + c;
  const int aoff0 = r0t * 64 + ((rg ^ ((r0t >> 1) & 3)) << 4);
  const int aoff1 = r1t * 64 + ((rg ^ ((r1t >> 1) & 3)) << 4);

#pragma unroll
  for (int kt = 0; kt < G2_NKT; ++kt) {
    const int curB = kt % 3;
    const int curA = kt & 1;
    bf16x8 a0 = *(const bf16x8*)&ab[curA][aoff0];
    bf16x8 a1 = *(const bf16x8*)&ab[curA][aoff1];
    bf16x8 bfr[5];
#pragma unroll
    for (int g = 0; g < 5; ++g)
      bfr[g] = *(const bf16x8*)&bb[curB][((((g << 2) + cw) << 6) + ln) * 16];
    if (kt + 1 < G2_NKT) storeA(curA ^ 1, av);
    if (kt + 2 < G2_NKT) {
      av = loadA(kt + 2);
      stageB(kt + 2, (kt + 2) % 3);
    }
#pragma unroll
    for (int g = 0; g < 5; ++g) {
      acc[0][g] = __builtin_amdgcn_mfma_f32_16x16x32_bf16(a0, bfr[g], acc[0][g], 0, 0, 0);
      acc[1][g] = __builtin_amdgcn_mfma_f32_16x16x32_bf16(a1, bfr[g], acc[1][g], 0, 0, 0);
    }
    if (kt + 1 < G2_NKT) {
      if (kt + 2 < G2_NKT) {
        asm volatile("s_waitcnt vmcnt(4) lgkmcnt(0)" ::: "memory");
      } else {
        asm volatile("s_waitcnt vmcnt(0) lgkmcnt(0)" ::: "memory");
      }
      __builtin_amdgcn_s_barrier();
    }
  }

  const int m = mb * 64 + cw * 16 + c;
  if (m < 168) {
#pragma unroll
    for (int rt = 0; rt < 2; ++rt) {
#pragma unroll
      for (int reg = 0; reg < 4; ++reg) {
        const int row = rbase + rt * 16 + (rg << 2) + reg;
        if (row >= NROWS) continue;
        const float i2 = acc[rt][0][reg];
        const float o2 = acc[rt][1][reg];
        const float fl2 = acc[rt][2][reg];
        const float fd2 = acc[rt][3][reg];
        const float u2 = acc[rt][4][reg];
        const int off = row * 168 + m;
        const float c1 = b2f(c1buf[off]);
        const float qv = q[off];
        const float c2 = sigf(i2) * tanh_f(u2) + sigf(fd2) * qv + sigf(fl2) * c1;
        const float h2 = sigf(o2) * tanh_f(c2);
        out[row * 336 + m] = h2;
        out[row * 336 + 168 + m] = c2;
      }
    }
  }
}

extern "C" void kernel_launch(void* const* d_in, const int* in_sizes, int n_in,
                              void* d_out, int out_size, void* d_ws, size_t ws_size,
                              hipStream_t stream) {
  const float* e     = (const float*)d_in[0];
  const float* tag   = (const float*)d_in[1];
  const float* tagp  = (const float*)d_in[2];
  const float* hprev = (const float*)d_in[3];
  const float* cprev = (const float*)d_in[4];
  const float* kk    = (const float*)d_in[5];
  const float* q     = (const float*)d_in[6];
  const float* We_l  = (const float*)d_in[7];
  const float* Wt_l  = (const float*)d_in[8];
  const float* Wtp_l = (const float*)d_in[9];
  const float* Uh_l  = (const float*)d_in[10];
  const float* b_l   = (const float*)d_in[11];
  const float* Wt_n  = (const float*)d_in[12];
  const float* Wtp_n = (const float*)d_in[13];
  const float* Uh_n  = (const float*)d_in[14];
  const float* Uk_n  = (const float*)d_in[15];
  const float* b_n   = (const float*)d_in[16];
  float* out = (float*)d_out;

  char* ws = (char*)d_ws;
  unsigned short* B1 = (unsigned short*)ws;                               // 884,736 B
  unsigned short* B2 = (unsigned short*)(ws + (1 << 20));                 // 1,032,192 B
  unsigned short* c1buf = (unsigned short*)(ws + (3 << 20));              // 33,600,000 B
  unsigned short* h1buf = (unsigned short*)(ws + (3 << 20) + 33600000);   // 33,600,000 B

  const int NB = 18 * 3 * 16 * 512 + 14 * 3 * 24 * 512;
  pack_weights<<<(NB + 255) / 256, 256, 0, stream>>>(We_l, Wt_l, Wtp_l, Uh_l, b_l,
                                                     Wt_n, Wtp_n, Uh_n, Uk_n, b_n, B1, B2);

  // XCD-sibling launch: b = (rowblk/8*3 + mb)*8 + rowblk%8; max j = 587 -> 4704 blocks
  const int nblk = 4704;
  gemm1_kernel<<<nblk, 512, 0, stream>>>(e, tag, tagp, hprev, cprev,
                                         (const char*)B1, c1buf, h1buf);
  gemm2_kernel<<<nblk, 512, 0, stream>>>(tag, tagp, kk, q,
                                         (const char*)B2, c1buf, h1buf, out);
}